// Round 1
// baseline (285.730 us; speedup 1.0000x reference)
//
#include <hip/hip_runtime.h>

#define S_TOT 4096
#define C_DIM 768
#define QKV_LD 2304

using f32x4  = __attribute__((ext_vector_type(4))) float;
using bf16x8 = __attribute__((ext_vector_type(8))) __bf16;

__device__ inline unsigned short f2bf_bits(float f) {
  unsigned int u = __float_as_uint(f);
  u = (u + 0x7FFFu + ((u >> 16) & 1u)) >> 16;
  return (unsigned short)u;
}
__device__ inline __bf16 f2bf(float f) {
  unsigned short s = f2bf_bits(f);
  __bf16 b;
  __builtin_memcpy(&b, &s, 2);
  return b;
}

__global__ void cvt_f32_bf16(const float* __restrict__ in, __bf16* __restrict__ out, int n) {
  int i = (blockIdx.x * blockDim.x + threadIdx.x) * 4;
  if (i < n) {
    float4 v = *reinterpret_cast<const float4*>(in + i);
    ushort4 o;
    o.x = f2bf_bits(v.x); o.y = f2bf_bits(v.y); o.z = f2bf_bits(v.z); o.w = f2bf_bits(v.w);
    *reinterpret_cast<ushort4*>(reinterpret_cast<unsigned short*>(out) + i) = o;
  }
}

// C = A @ B^T where A is [M][K] bf16 row-major, B is [N][K] bf16 row-major.
// Tile 64x64, BK=64, 4 waves in 2x2 grid, each wave 32x32 via 2x2 mfma_16x16x32.
template<bool OUT_BIAS_F32>
__global__ __launch_bounds__(256) void gemm_xwT(
    const __bf16* __restrict__ A, const __bf16* __restrict__ B,
    void* __restrict__ Cv, const float* __restrict__ bias, int K, int ldc) {
  __shared__ __bf16 As[64][72];   // stride 72 -> 2-way bank conflict only (free)
  __shared__ __bf16 Bs[64][72];
  const int t = threadIdx.x;
  const int lane = t & 63, wv = t >> 6;
  const int wr = wv >> 1, wc = wv & 1;
  const int lhi = lane >> 4, llo = lane & 15;
  const int m0 = blockIdx.y * 64, n0 = blockIdx.x * 64;

  f32x4 acc[2][2];
  #pragma unroll
  for (int a = 0; a < 2; ++a)
    #pragma unroll
    for (int b = 0; b < 2; ++b) acc[a][b] = (f32x4){0.f, 0.f, 0.f, 0.f};

  const int r = t >> 2, c = (t & 3) * 8;
  for (int kt = 0; kt < K; kt += 64) {
    __syncthreads();
    const __bf16* gA = A + (size_t)(m0 + r) * K + kt + c;
    *reinterpret_cast<uint4*>(&As[r][c])      = *reinterpret_cast<const uint4*>(gA);
    *reinterpret_cast<uint4*>(&As[r][c + 32]) = *reinterpret_cast<const uint4*>(gA + 32);
    const __bf16* gB = B + (size_t)(n0 + r) * K + kt + c;
    *reinterpret_cast<uint4*>(&Bs[r][c])      = *reinterpret_cast<const uint4*>(gB);
    *reinterpret_cast<uint4*>(&Bs[r][c + 32]) = *reinterpret_cast<const uint4*>(gB + 32);
    __syncthreads();
    #pragma unroll
    for (int kk = 0; kk < 2; ++kk) {
      bf16x8 af[2], bfr[2];
      #pragma unroll
      for (int mi = 0; mi < 2; ++mi)
        af[mi] = *reinterpret_cast<const bf16x8*>(&As[wr * 32 + mi * 16 + llo][kk * 32 + lhi * 8]);
      #pragma unroll
      for (int ni = 0; ni < 2; ++ni)
        bfr[ni] = *reinterpret_cast<const bf16x8*>(&Bs[wc * 32 + ni * 16 + llo][kk * 32 + lhi * 8]);
      #pragma unroll
      for (int mi = 0; mi < 2; ++mi)
        #pragma unroll
        for (int ni = 0; ni < 2; ++ni)
          acc[mi][ni] = __builtin_amdgcn_mfma_f32_16x16x32_bf16(af[mi], bfr[ni], acc[mi][ni], 0, 0, 0);
    }
  }
  #pragma unroll
  for (int mi = 0; mi < 2; ++mi)
    #pragma unroll
    for (int ni = 0; ni < 2; ++ni)
      #pragma unroll
      for (int i = 0; i < 4; ++i) {
        int row = m0 + wr * 32 + mi * 16 + lhi * 4 + i;
        int col = n0 + wc * 32 + ni * 16 + llo;
        if constexpr (OUT_BIAS_F32) {
          reinterpret_cast<float*>(Cv)[(size_t)row * ldc + col] = acc[mi][ni][i] + bias[col];
        } else {
          reinterpret_cast<__bf16*>(Cv)[(size_t)row * ldc + col] = f2bf(acc[mi][ni][i]);
        }
      }
}

// Flash attention over QKV [4096][2304] bf16 (Q cols 0..767, K 768..1535, V 1536..2303).
// Block: head h x 64-row q-tile; 4 waves, each owns 16 q rows. Mask is view-block
// granular: q-view<=1 -> keys [0,1024); q-view v>=2 -> keys [0,(v+1)*512).
__global__ __launch_bounds__(256) void attn_fused(
    const __bf16* __restrict__ QKV, __bf16* __restrict__ att) {
  __shared__ __bf16 Ks[64][72];
  __shared__ __bf16 Vt[64][72];     // V transposed: Vt[d][key]
  __shared__ __bf16 Ps[4][16][72];  // per-wave P transpose buffer
  const int t = threadIdx.x, lane = t & 63, wv = t >> 6;
  const int lhi = lane >> 4, llo = lane & 15;
  const int h = blockIdx.y;
  const int qb = blockIdx.x;
  const int q0 = qb * 64 + wv * 16;
  const int vq = (qb * 64) >> 9;
  const int kv_end = (vq <= 1) ? 1024 : (vq + 1) * 512;

  bf16x8 qf[2];
  #pragma unroll
  for (int kk = 0; kk < 2; ++kk)
    qf[kk] = *reinterpret_cast<const bf16x8*>(
        QKV + (size_t)(q0 + llo) * QKV_LD + h * 64 + kk * 32 + lhi * 8);

  f32x4 Oa[4];
  float m_r[4], l_r[4];
  #pragma unroll
  for (int i = 0; i < 4; ++i) { Oa[i] = (f32x4){0.f, 0.f, 0.f, 0.f}; m_r[i] = -INFINITY; l_r[i] = 0.f; }

  const int r = t >> 2, c = (t & 3) * 8;
  for (int k0 = 0; k0 < kv_end; k0 += 64) {
    __syncthreads();
    const __bf16* gK = QKV + (size_t)(k0 + r) * QKV_LD + 768 + h * 64 + c;
    *reinterpret_cast<uint4*>(&Ks[r][c])      = *reinterpret_cast<const uint4*>(gK);
    *reinterpret_cast<uint4*>(&Ks[r][c + 32]) = *reinterpret_cast<const uint4*>(gK + 32);
    const __bf16* gV = QKV + (size_t)(k0 + r) * QKV_LD + 1536 + h * 64 + c;
    #pragma unroll
    for (int pass = 0; pass < 2; ++pass) {
      bf16x8 vvv = *reinterpret_cast<const bf16x8*>(gV + pass * 32);
      #pragma unroll
      for (int j = 0; j < 8; ++j) Vt[c + pass * 32 + j][r] = vvv[j];
    }
    __syncthreads();

    // scores: 16 q x 64 keys per wave
    f32x4 sc[4];
    #pragma unroll
    for (int nt = 0; nt < 4; ++nt) sc[nt] = (f32x4){0.f, 0.f, 0.f, 0.f};
    #pragma unroll
    for (int kk = 0; kk < 2; ++kk)
      #pragma unroll
      for (int nt = 0; nt < 4; ++nt) {
        bf16x8 kf = *reinterpret_cast<const bf16x8*>(&Ks[nt * 16 + llo][kk * 32 + lhi * 8]);
        sc[nt] = __builtin_amdgcn_mfma_f32_16x16x32_bf16(qf[kk], kf, sc[nt], 0, 0, 0);
      }
    #pragma unroll
    for (int nt = 0; nt < 4; ++nt)
      #pragma unroll
      for (int i = 0; i < 4; ++i) sc[nt][i] *= 0.125f;

    __bf16 pb[4][4];
    #pragma unroll
    for (int i = 0; i < 4; ++i) {
      float mx = fmaxf(fmaxf(sc[0][i], sc[1][i]), fmaxf(sc[2][i], sc[3][i]));
      #pragma unroll
      for (int d = 1; d < 16; d <<= 1) mx = fmaxf(mx, __shfl_xor(mx, d, 64));
      float mnew = fmaxf(m_r[i], mx);
      float alpha = __expf(m_r[i] - mnew);
      m_r[i] = mnew;
      float rs = 0.f;
      #pragma unroll
      for (int nt = 0; nt < 4; ++nt) {
        float p = __expf(sc[nt][i] - mnew);
        rs += p;
        pb[nt][i] = f2bf(p);
      }
      #pragma unroll
      for (int d = 1; d < 16; d <<= 1) rs += __shfl_xor(rs, d, 64);
      l_r[i] = l_r[i] * alpha + rs;
      #pragma unroll
      for (int nt = 0; nt < 4; ++nt) Oa[nt][i] *= alpha;
    }
    // P -> per-wave LDS (transpose to A-operand layout); same-wave DS ordering is safe
    #pragma unroll
    for (int nt = 0; nt < 4; ++nt)
      #pragma unroll
      for (int i = 0; i < 4; ++i)
        Ps[wv][lhi * 4 + i][nt * 16 + llo] = pb[nt][i];
    #pragma unroll
    for (int kk = 0; kk < 2; ++kk) {
      bf16x8 pa = *reinterpret_cast<const bf16x8*>(&Ps[wv][llo][kk * 32 + lhi * 8]);
      #pragma unroll
      for (int nt = 0; nt < 4; ++nt) {
        bf16x8 vf = *reinterpret_cast<const bf16x8*>(&Vt[nt * 16 + llo][kk * 32 + lhi * 8]);
        Oa[nt] = __builtin_amdgcn_mfma_f32_16x16x32_bf16(pa, vf, Oa[nt], 0, 0, 0);
      }
    }
  }
  #pragma unroll
  for (int nt = 0; nt < 4; ++nt)
    #pragma unroll
    for (int i = 0; i < 4; ++i) {
      int row = q0 + lhi * 4 + i;
      int col = h * 64 + nt * 16 + llo;
      att[(size_t)row * C_DIM + col] = f2bf(Oa[nt][i] / l_r[i]);
    }
}

extern "C" void kernel_launch(void* const* d_in, const int* in_sizes, int n_in,
                              void* d_out, int out_size, void* d_ws, size_t ws_size,
                              hipStream_t stream) {
  const float* x  = (const float*)d_in[0];
  const float* Wq = (const float*)d_in[1];
  const float* Wk = (const float*)d_in[2];
  const float* Wv = (const float*)d_in[3];
  const float* Wo = (const float*)d_in[4];
  const float* bo = (const float*)d_in[5];

  __bf16* xb   = (__bf16*)d_ws;                          // [4096][768]
  __bf16* Wqkv = xb + (size_t)S_TOT * C_DIM;             // [2304][768] rows: Wq,Wk,Wv
  __bf16* Wob  = Wqkv + (size_t)3 * C_DIM * C_DIM;       // [768][768]
  __bf16* QKV  = Wob + (size_t)C_DIM * C_DIM;            // [4096][2304]
  __bf16* att  = QKV + (size_t)S_TOT * QKV_LD;           // [4096][768]

  auto cvt = [&](const float* src, __bf16* dst, int n) {
    cvt_f32_bf16<<<dim3((n / 4 + 255) / 256), dim3(256), 0, stream>>>(src, dst, n);
  };
  cvt(x, xb, S_TOT * C_DIM);
  cvt(Wq, Wqkv, C_DIM * C_DIM);
  cvt(Wk, Wqkv + (size_t)C_DIM * C_DIM, C_DIM * C_DIM);
  cvt(Wv, Wqkv + (size_t)2 * C_DIM * C_DIM, C_DIM * C_DIM);
  cvt(Wo, Wob, C_DIM * C_DIM);

  // QKV = xb @ Wqkv^T : [4096][2304]
  gemm_xwT<false><<<dim3(QKV_LD / 64, S_TOT / 64), dim3(256), 0, stream>>>(
      xb, Wqkv, (void*)QKV, nullptr, C_DIM, QKV_LD);

  // flash attention -> att [4096][768]
  attn_fused<<<dim3(S_TOT / 64, 12), dim3(256), 0, stream>>>(QKV, att);

  // out = att @ Wo^T + bo : f32 [4096][768]
  gemm_xwT<true><<<dim3(C_DIM / 64, S_TOT / 64), dim3(256), 0, stream>>>(
      att, Wob, d_out, bo, C_DIM, C_DIM);
}